// Round 3
// baseline (303.855 us; speedup 1.0000x reference)
//
#include <hip/hip_runtime.h>

#define D 128

typedef unsigned short u16;
typedef __attribute__((ext_vector_type(8))) short bf16x8;
typedef __attribute__((ext_vector_type(4))) float f32x4;

__device__ __forceinline__ u16 f32_to_bf16(float f) {
    unsigned u = __float_as_uint(f);
    unsigned rounding = 0x7fffu + ((u >> 16) & 1u);   // round-to-nearest-even
    return (u16)((u + rounding) >> 16);
}

__device__ __forceinline__ float bf16_to_f32(u16 s) {
    return __uint_as_float(((unsigned)s) << 16);
}

// -------------------------------------------------------------------------
// Kernel 0: Wt[n][k] = bf16(W[k][n]).  16384 elements, 64 blocks.
// -------------------------------------------------------------------------
__global__ __launch_bounds__(256) void prep_kernel(
    const float* __restrict__ W, u16* __restrict__ Wt)
{
    int idx = blockIdx.x * 256 + threadIdx.x;   // idx = n*128 + k
    int n = idx >> 7;
    int k = idx & 127;
    Wt[idx] = f32_to_bf16(W[k * 128 + n]);
}

// -------------------------------------------------------------------------
// Kernel 1: support = bf16(x @ W + b) via MFMA 16x16x32 bf16.
// No LDS. Block = 256 (4 waves); wave w owns rows [blk*64 + w*16, +16).
// x split into hi+lo bf16 (2 MFMAs) -> only W rounding + final store error.
// -------------------------------------------------------------------------
__global__ __launch_bounds__(256) void gemm_mfma_kernel(
    const float* __restrict__ x, const u16* __restrict__ Wt,
    const float* __restrict__ b, u16* __restrict__ sup, int N)
{
    const int lane = threadIdx.x & 63;
    const int wave = threadIdx.x >> 6;
    const int col  = lane & 15;
    const int quad = lane >> 4;
    const int row0 = blockIdx.x * 64 + wave * 16;
    const int m    = row0 + col;
    const bool mvalid = (m < N);

    f32x4 acc[8];
    #pragma unroll
    for (int nt = 0; nt < 8; ++nt) {
        float bias = b[nt * 16 + col];
        acc[nt][0] = bias; acc[nt][1] = bias;
        acc[nt][2] = bias; acc[nt][3] = bias;
    }

    const float* xrow = x + (size_t)m * D;

    #pragma unroll
    for (int ks = 0; ks < 4; ++ks) {
        const int k0 = ks * 32 + quad * 8;

        float af[8];
        if (mvalid) {
            float4 v0 = *(const float4*)(xrow + k0);
            float4 v1 = *(const float4*)(xrow + k0 + 4);
            af[0] = v0.x; af[1] = v0.y; af[2] = v0.z; af[3] = v0.w;
            af[4] = v1.x; af[5] = v1.y; af[6] = v1.z; af[7] = v1.w;
        } else {
            #pragma unroll
            for (int j = 0; j < 8; ++j) af[j] = 0.f;
        }

        bf16x8 ahi, alo;
        #pragma unroll
        for (int j = 0; j < 8; ++j) {
            u16 h = f32_to_bf16(af[j]);
            float r = af[j] - bf16_to_f32(h);
            ahi[j] = (short)h;
            alo[j] = (short)f32_to_bf16(r);
        }

        #pragma unroll
        for (int nt = 0; nt < 8; ++nt) {
            bf16x8 bfrag = *(const bf16x8*)(Wt + (size_t)(nt * 16 + col) * D + k0);
            acc[nt] = __builtin_amdgcn_mfma_f32_16x16x32_bf16(alo, bfrag, acc[nt], 0, 0, 0);
            acc[nt] = __builtin_amdgcn_mfma_f32_16x16x32_bf16(ahi, bfrag, acc[nt], 0, 0, 0);
        }
    }

    #pragma unroll
    for (int reg = 0; reg < 4; ++reg) {
        int r = row0 + quad * 4 + reg;
        if (r < N) {
            #pragma unroll
            for (int nt = 0; nt < 8; ++nt) {
                sup[(size_t)r * D + nt * 16 + col] = f32_to_bf16(acc[nt][reg]);
            }
        }
    }
}

// -------------------------------------------------------------------------
// Kernel 2: row_ptr from sorted edge_dst. rp[n] = lower_bound(edge_dst, n).
// -------------------------------------------------------------------------
__global__ __launch_bounds__(256) void rowptr_kernel(
    const int* __restrict__ edst, int* __restrict__ rp, int E, int N)
{
    int e = blockIdx.x * 256 + threadIdx.x;
    if (e >= E) return;
    int d = edst[e];
    int prev = (e == 0) ? -1 : edst[e - 1];
    for (int n = prev + 1; n <= d; ++n) rp[n] = e;
    if (e == E - 1) {
        for (int n = d + 1; n <= N; ++n) rp[n] = E;
    }
}

// -------------------------------------------------------------------------
// Kernel 3: SpMM. One wave per destination node. Segment bounds are forced
// wave-uniform via readfirstlane, so all edge metadata (esrc/ew) is indexed
// by uniform expressions -> compiler emits scalar s_loads (no ds_bpermute,
// no per-lane address math). Metadata for the NEXT 8-edge block is
// prefetched while the current 8 row-gathers are in flight. Tail edges are
// clamped to index e (in-segment, weight forced to 0).
// -------------------------------------------------------------------------
__global__ __launch_bounds__(256) void spmm_kernel(
    const u16* __restrict__ sup, const float* __restrict__ ew,
    const int* __restrict__ esrc, const int* __restrict__ rp,
    float* __restrict__ out, int N)
{
    const int wid  = (blockIdx.x * 256 + threadIdx.x) >> 6;
    const int lane = threadIdx.x & 63;
    if (wid >= N) return;

    const int start = __builtin_amdgcn_readfirstlane(rp[wid]);
    const int end   = __builtin_amdgcn_readfirstlane(rp[wid + 1]);
    const unsigned off = (unsigned)lane * 2u;

    float acc0 = 0.f, acc1 = 0.f, acc2 = 0.f, acc3 = 0.f;

    int   sm[8];
    float wm[8];

    if (start < end) {
        #pragma unroll
        for (int k = 0; k < 8; ++k) {
            int ik  = start + k;
            int idx = (ik < end) ? ik : start;
            sm[k] = esrc[idx];
            wm[k] = (ik < end) ? ew[idx] : 0.f;
        }
    }

    for (int e = start; e < end; e += 8) {
        int   cs[8];
        float cw[8];
        #pragma unroll
        for (int k = 0; k < 8; ++k) { cs[k] = sm[k]; cw[k] = wm[k]; }

        // Issue the 8 independent row gathers.
        unsigned u[8];
        #pragma unroll
        for (int k = 0; k < 8; ++k) {
            u[k] = *(const unsigned*)(sup + (size_t)cs[k] * D + off);
        }

        // Prefetch next metadata block (scalar loads, overlap the gathers).
        int en = e + 8;
        if (en < end) {
            #pragma unroll
            for (int k = 0; k < 8; ++k) {
                int ik  = en + k;
                int idx = (ik < end) ? ik : en;
                sm[k] = esrc[idx];
                wm[k] = (ik < end) ? ew[idx] : 0.f;
            }
        }

        #pragma unroll
        for (int k = 0; k < 8; ++k) {
            float lo = __uint_as_float(u[k] << 16);
            float hi = __uint_as_float(u[k] & 0xffff0000u);
            if (k & 1) {
                acc2 = fmaf(cw[k], lo, acc2);
                acc3 = fmaf(cw[k], hi, acc3);
            } else {
                acc0 = fmaf(cw[k], lo, acc0);
                acc1 = fmaf(cw[k], hi, acc1);
            }
        }
    }

    float2 o;
    o.x = acc0 + acc2;
    o.y = acc1 + acc3;
    *(float2*)(out + (size_t)wid * D + off) = o;
}

extern "C" void kernel_launch(void* const* d_in, const int* in_sizes, int n_in,
                              void* d_out, int out_size, void* d_ws, size_t ws_size,
                              hipStream_t stream) {
    const float* x    = (const float*)d_in[0];
    const float* W    = (const float*)d_in[1];
    const float* b    = (const float*)d_in[2];
    const float* ew   = (const float*)d_in[3];
    const int*   esrc = (const int*)d_in[4];
    const int*   edst = (const int*)d_in[5];
    float* out = (float*)d_out;

    const int N = in_sizes[0] / D;
    const int E = in_sizes[3];

    u16* sup = (u16*)d_ws;                                        // N*128 bf16
    int* rp  = (int*)((char*)d_ws + (size_t)N * D * sizeof(u16)); // N+1 ints
    u16* Wt  = (u16*)((char*)rp + ((size_t)N + 16) * sizeof(int));// 128*128 bf16

    hipLaunchKernelGGL(prep_kernel, dim3(64), dim3(256), 0, stream, W, Wt);
    hipLaunchKernelGGL(gemm_mfma_kernel, dim3((N + 63) / 64), dim3(256), 0, stream,
                       x, Wt, b, sup, N);
    hipLaunchKernelGGL(rowptr_kernel, dim3((E + 255) / 256), dim3(256), 0, stream,
                       edst, rp, E, N);
    hipLaunchKernelGGL(spmm_kernel, dim3((N + 3) / 4), dim3(256), 0, stream,
                       sup, ew, esrc, rp, out, N);
}

// Round 4
// 261.635 us; speedup vs baseline: 1.1614x; 1.1614x over previous
//
#include <hip/hip_runtime.h>

#define D 128

typedef unsigned short u16;
typedef __attribute__((ext_vector_type(8))) short bf16x8;
typedef __attribute__((ext_vector_type(4))) float f32x4;

__device__ __forceinline__ u16 f32_to_bf16(float f) {
    unsigned u = __float_as_uint(f);
    unsigned rounding = 0x7fffu + ((u >> 16) & 1u);   // round-to-nearest-even
    return (u16)((u + rounding) >> 16);
}

__device__ __forceinline__ float bf16_to_f32(u16 s) {
    return __uint_as_float(((unsigned)s) << 16);
}

// -------------------------------------------------------------------------
// Kernel 0: Wt[n][k] = bf16(W[k][n]).  16384 elements, 64 blocks.
// -------------------------------------------------------------------------
__global__ __launch_bounds__(256) void prep_kernel(
    const float* __restrict__ W, u16* __restrict__ Wt)
{
    int idx = blockIdx.x * 256 + threadIdx.x;   // idx = n*128 + k
    int n = idx >> 7;
    int k = idx & 127;
    Wt[idx] = f32_to_bf16(W[k * 128 + n]);
}

// -------------------------------------------------------------------------
// Kernel 1: support = bf16(x @ W + b) via MFMA 16x16x32 bf16.  (unchanged R2)
// -------------------------------------------------------------------------
__global__ __launch_bounds__(256) void gemm_mfma_kernel(
    const float* __restrict__ x, const u16* __restrict__ Wt,
    const float* __restrict__ b, u16* __restrict__ sup, int N)
{
    const int lane = threadIdx.x & 63;
    const int wave = threadIdx.x >> 6;
    const int col  = lane & 15;
    const int quad = lane >> 4;
    const int row0 = blockIdx.x * 64 + wave * 16;
    const int m    = row0 + col;
    const bool mvalid = (m < N);

    f32x4 acc[8];
    #pragma unroll
    for (int nt = 0; nt < 8; ++nt) {
        float bias = b[nt * 16 + col];
        acc[nt][0] = bias; acc[nt][1] = bias;
        acc[nt][2] = bias; acc[nt][3] = bias;
    }

    const float* xrow = x + (size_t)m * D;

    #pragma unroll
    for (int ks = 0; ks < 4; ++ks) {
        const int k0 = ks * 32 + quad * 8;

        float af[8];
        if (mvalid) {
            float4 v0 = *(const float4*)(xrow + k0);
            float4 v1 = *(const float4*)(xrow + k0 + 4);
            af[0] = v0.x; af[1] = v0.y; af[2] = v0.z; af[3] = v0.w;
            af[4] = v1.x; af[5] = v1.y; af[6] = v1.z; af[7] = v1.w;
        } else {
            #pragma unroll
            for (int j = 0; j < 8; ++j) af[j] = 0.f;
        }

        bf16x8 ahi, alo;
        #pragma unroll
        for (int j = 0; j < 8; ++j) {
            u16 h = f32_to_bf16(af[j]);
            float r = af[j] - bf16_to_f32(h);
            ahi[j] = (short)h;
            alo[j] = (short)f32_to_bf16(r);
        }

        #pragma unroll
        for (int nt = 0; nt < 8; ++nt) {
            bf16x8 bfrag = *(const bf16x8*)(Wt + (size_t)(nt * 16 + col) * D + k0);
            acc[nt] = __builtin_amdgcn_mfma_f32_16x16x32_bf16(alo, bfrag, acc[nt], 0, 0, 0);
            acc[nt] = __builtin_amdgcn_mfma_f32_16x16x32_bf16(ahi, bfrag, acc[nt], 0, 0, 0);
        }
    }

    #pragma unroll
    for (int reg = 0; reg < 4; ++reg) {
        int r = row0 + quad * 4 + reg;
        if (r < N) {
            #pragma unroll
            for (int nt = 0; nt < 8; ++nt) {
                sup[(size_t)r * D + nt * 16 + col] = f32_to_bf16(acc[nt][reg]);
            }
        }
    }
}

// -------------------------------------------------------------------------
// Kernel 2: row_ptr from sorted edge_dst. rp[n] = lower_bound(edge_dst, n).
// -------------------------------------------------------------------------
__global__ __launch_bounds__(256) void rowptr_kernel(
    const int* __restrict__ edst, int* __restrict__ rp, int E, int N)
{
    int e = blockIdx.x * 256 + threadIdx.x;
    if (e >= E) return;
    int d = edst[e];
    int prev = (e == 0) ? -1 : edst[e - 1];
    for (int n = prev + 1; n <= d; ++n) rp[n] = e;
    if (e == E - 1) {
        for (int n = d + 1; n <= N; ++n) rp[n] = E;
    }
}

// -------------------------------------------------------------------------
// Kernel 3: SpMM, XCD-partitioned by feature half.
// blockIdx % 8 maps round-robin to XCDs: XCDs 0-3 process feature half 0
// (bytes 0..127 of each support row), XCDs 4-7 half 1. Per-XCD gather
// working set: 12.8 MB instead of 25.6 MB -> higher L2 hit rate, lower
// FETCH_SIZE. One wave per (node, half); a 64-feat half is 32 dwords, so
// lane-halves process two edges per gather instruction (16 edges/iter in
// flight). Metadata loaded coalesced + broadcast via __shfl (R2 scheme).
// -------------------------------------------------------------------------
__global__ __launch_bounds__(256) void spmm_kernel(
    const u16* __restrict__ sup, const float* __restrict__ ew,
    const int* __restrict__ esrc, const int* __restrict__ rp,
    float* __restrict__ out, int N)
{
    const int b    = blockIdx.x;
    const int xcd  = b & 7;
    const int half = xcd >> 2;                   // 0: feats 0-63, 1: feats 64-127
    const int grp  = (b >> 3) * 4 + (xcd & 3);   // block group within the half
    const int wave = threadIdx.x >> 6;
    const int lane = threadIdx.x & 63;
    const int node = grp * 4 + wave;
    if (node >= N) return;

    const int start = rp[node];
    const int end   = rp[node + 1];

    const int eh = lane >> 5;                    // which edge of the lane-pair
    const unsigned off = (unsigned)half * 64u + (unsigned)(lane & 31) * 2u;

    float acc0 = 0.f, acc1 = 0.f, acc2 = 0.f, acc3 = 0.f;

    for (int base = start; base < end; base += 64) {
        int cnt = end - base;
        if (cnt > 64) cnt = 64;
        int cnt16 = (cnt + 15) & ~15;

        int mi = base + lane;
        int   sv = (mi < end) ? esrc[mi] : 0;
        float wv = (mi < end) ? ew[mi]   : 0.f;

        for (int i = 0; i < cnt16; i += 16) {
            int s[8]; float w[8];
            #pragma unroll
            for (int k = 0; k < 8; ++k) {
                int idx = i + 2 * k + eh;        // lanes 0-31: edge i+2k, 32-63: i+2k+1
                s[k] = __shfl(sv, idx);
                w[k] = __shfl(wv, idx);
            }

            unsigned u[8];
            #pragma unroll
            for (int k = 0; k < 8; ++k) {
                u[k] = *(const unsigned*)(sup + (size_t)s[k] * D + off);
            }

            #pragma unroll
            for (int k = 0; k < 8; ++k) {
                float lo = __uint_as_float(u[k] << 16);
                float hi = __uint_as_float(u[k] & 0xffff0000u);
                if (k & 1) {
                    acc2 = fmaf(w[k], lo, acc2);
                    acc3 = fmaf(w[k], hi, acc3);
                } else {
                    acc0 = fmaf(w[k], lo, acc0);
                    acc1 = fmaf(w[k], hi, acc1);
                }
            }
        }
    }

    float a0 = acc0 + acc2;
    float a1 = acc1 + acc3;
    // Combine the two lane-halves (they hold alternating edges of the same
    // (node, half) segment, same feature dword).
    a0 += __shfl_xor(a0, 32);
    a1 += __shfl_xor(a1, 32);

    if (lane < 32) {
        float2 o;
        o.x = a0;
        o.y = a1;
        *(float2*)(out + (size_t)node * D + off) = o;
    }
}

extern "C" void kernel_launch(void* const* d_in, const int* in_sizes, int n_in,
                              void* d_out, int out_size, void* d_ws, size_t ws_size,
                              hipStream_t stream) {
    const float* x    = (const float*)d_in[0];
    const float* W    = (const float*)d_in[1];
    const float* b    = (const float*)d_in[2];
    const float* ew   = (const float*)d_in[3];
    const int*   esrc = (const int*)d_in[4];
    const int*   edst = (const int*)d_in[5];
    float* out = (float*)d_out;

    const int N = in_sizes[0] / D;
    const int E = in_sizes[3];

    u16* sup = (u16*)d_ws;                                        // N*128 bf16
    int* rp  = (int*)((char*)d_ws + (size_t)N * D * sizeof(u16)); // N+1 ints
    u16* Wt  = (u16*)((char*)rp + ((size_t)N + 16) * sizeof(int));// 128*128 bf16

    hipLaunchKernelGGL(prep_kernel, dim3(64), dim3(256), 0, stream, W, Wt);
    hipLaunchKernelGGL(gemm_mfma_kernel, dim3((N + 63) / 64), dim3(256), 0, stream,
                       x, Wt, b, sup, N);
    hipLaunchKernelGGL(rowptr_kernel, dim3((E + 255) / 256), dim3(256), 0, stream,
                       edst, rp, E, N);

    // Blocks per feature-half: ceil(N/4) waves-of-4. Grid interleaves halves
    // across XCD groups of 8 blocks (4 for half 0, 4 for half 1).
    int nblk_half = (N + 3) / 4;
    int grid_spmm = ((nblk_half + 3) / 4) * 8;
    hipLaunchKernelGGL(spmm_kernel, dim3(grid_spmm), dim3(256), 0, stream,
                       sup, ew, esrc, rp, out, N);
}

// Round 5
// 259.608 us; speedup vs baseline: 1.1704x; 1.0078x over previous
//
#include <hip/hip_runtime.h>

#define D 128

typedef unsigned short u16;
typedef __attribute__((ext_vector_type(8))) short bf16x8;
typedef __attribute__((ext_vector_type(4))) float f32x4;

__device__ __forceinline__ u16 f32_to_bf16(float f) {
    unsigned u = __float_as_uint(f);
    unsigned rounding = 0x7fffu + ((u >> 16) & 1u);   // round-to-nearest-even
    return (u16)((u + rounding) >> 16);
}

__device__ __forceinline__ float bf16_to_f32(u16 s) {
    return __uint_as_float(((unsigned)s) << 16);
}

// -------------------------------------------------------------------------
// Kernel 0: Wt[n][k] = bf16(W[k][n]).  16384 elements, 64 blocks.
// -------------------------------------------------------------------------
__global__ __launch_bounds__(256) void prep_kernel(
    const float* __restrict__ W, u16* __restrict__ Wt)
{
    int idx = blockIdx.x * 256 + threadIdx.x;   // idx = n*128 + k
    int n = idx >> 7;
    int k = idx & 127;
    Wt[idx] = f32_to_bf16(W[k * 128 + n]);
}

// -------------------------------------------------------------------------
// Kernel 1: support = bf16(x @ W + b) via MFMA 16x16x32 bf16.  (unchanged R2)
// -------------------------------------------------------------------------
__global__ __launch_bounds__(256) void gemm_mfma_kernel(
    const float* __restrict__ x, const u16* __restrict__ Wt,
    const float* __restrict__ b, u16* __restrict__ sup, int N)
{
    const int lane = threadIdx.x & 63;
    const int wave = threadIdx.x >> 6;
    const int col  = lane & 15;
    const int quad = lane >> 4;
    const int row0 = blockIdx.x * 64 + wave * 16;
    const int m    = row0 + col;
    const bool mvalid = (m < N);

    f32x4 acc[8];
    #pragma unroll
    for (int nt = 0; nt < 8; ++nt) {
        float bias = b[nt * 16 + col];
        acc[nt][0] = bias; acc[nt][1] = bias;
        acc[nt][2] = bias; acc[nt][3] = bias;
    }

    const float* xrow = x + (size_t)m * D;

    #pragma unroll
    for (int ks = 0; ks < 4; ++ks) {
        const int k0 = ks * 32 + quad * 8;

        float af[8];
        if (mvalid) {
            float4 v0 = *(const float4*)(xrow + k0);
            float4 v1 = *(const float4*)(xrow + k0 + 4);
            af[0] = v0.x; af[1] = v0.y; af[2] = v0.z; af[3] = v0.w;
            af[4] = v1.x; af[5] = v1.y; af[6] = v1.z; af[7] = v1.w;
        } else {
            #pragma unroll
            for (int j = 0; j < 8; ++j) af[j] = 0.f;
        }

        bf16x8 ahi, alo;
        #pragma unroll
        for (int j = 0; j < 8; ++j) {
            u16 h = f32_to_bf16(af[j]);
            float r = af[j] - bf16_to_f32(h);
            ahi[j] = (short)h;
            alo[j] = (short)f32_to_bf16(r);
        }

        #pragma unroll
        for (int nt = 0; nt < 8; ++nt) {
            bf16x8 bfrag = *(const bf16x8*)(Wt + (size_t)(nt * 16 + col) * D + k0);
            acc[nt] = __builtin_amdgcn_mfma_f32_16x16x32_bf16(alo, bfrag, acc[nt], 0, 0, 0);
            acc[nt] = __builtin_amdgcn_mfma_f32_16x16x32_bf16(ahi, bfrag, acc[nt], 0, 0, 0);
        }
    }

    #pragma unroll
    for (int reg = 0; reg < 4; ++reg) {
        int r = row0 + quad * 4 + reg;
        if (r < N) {
            #pragma unroll
            for (int nt = 0; nt < 8; ++nt) {
                sup[(size_t)r * D + nt * 16 + col] = f32_to_bf16(acc[nt][reg]);
            }
        }
    }
}

// -------------------------------------------------------------------------
// Kernel 2: row_ptr from sorted edge_dst. rp[n] = lower_bound(edge_dst, n).
// -------------------------------------------------------------------------
__global__ __launch_bounds__(256) void rowptr_kernel(
    const int* __restrict__ edst, int* __restrict__ rp, int E, int N)
{
    int e = blockIdx.x * 256 + threadIdx.x;
    if (e >= E) return;
    int d = edst[e];
    int prev = (e == 0) ? -1 : edst[e - 1];
    for (int n = prev + 1; n <= d; ++n) rp[n] = e;
    if (e == E - 1) {
        for (int n = d + 1; n <= N; ++n) rp[n] = E;
    }
}

// -------------------------------------------------------------------------
// Kernel 3: SpMM, XCD-partitioned by feature half, dwordx4 gathers.
// One wave per (node, half). A 64-feat half-row is 128 B; each lane loads
// 16 B (8 bf16 feats), so 8 lanes cover a half-row and ONE load instruction
// gathers 8 edges (vs 2 in R4). Gather-instruction count drops 4x and
// bytes-in-flight per wave doubles -> attacks the queueing equilibrium.
// lane = eg*8 + fl: eg = edge-group (0..7), fl = feature-octet (0..7).
// After the loop, reduce across edge-groups with 3 shfl_xor rounds.
// -------------------------------------------------------------------------
__global__ __launch_bounds__(256) void spmm_kernel(
    const u16* __restrict__ sup, const float* __restrict__ ew,
    const int* __restrict__ esrc, const int* __restrict__ rp,
    float* __restrict__ out, int N)
{
    const int b    = blockIdx.x;
    const int xcd  = b & 7;
    const int half = xcd >> 2;                   // 0: feats 0-63, 1: feats 64-127
    const int grp  = (b >> 3) * 4 + (xcd & 3);   // block group within the half
    const int wave = threadIdx.x >> 6;
    const int lane = threadIdx.x & 63;
    const int node = grp * 4 + wave;
    if (node >= N) return;

    const int start = rp[node];
    const int end   = rp[node + 1];

    const int eg = lane >> 3;                    // edge-group within an iter
    const int fl = lane & 7;                     // feature octet owner
    const unsigned off = (unsigned)half * 64u + (unsigned)fl * 8u;  // u16 units

    float acc[8];
    #pragma unroll
    for (int j = 0; j < 8; ++j) acc[j] = 0.f;

    for (int base = start; base < end; base += 64) {
        int cnt = end - base;
        if (cnt > 64) cnt = 64;

        int mi = base + lane;
        int   sv = (mi < end) ? esrc[mi] : 0;
        float wv = (mi < end) ? ew[mi]   : 0.f;

        for (int i = 0; i < cnt; i += 32) {
            uint4 u[4];
            float w[4];
            #pragma unroll
            for (int g = 0; g < 4; ++g) {
                int idx  = i + g * 8 + eg;
                int cidx = (idx < cnt) ? idx : (cnt - 1);
                int   s  = __shfl(sv, cidx);
                float wt = __shfl(wv, cidx);
                w[g] = (idx < cnt) ? wt : 0.f;
                u[g] = *(const uint4*)(sup + (size_t)s * D + off);
            }
            #pragma unroll
            for (int g = 0; g < 4; ++g) {
                unsigned d0 = u[g].x, d1 = u[g].y, d2 = u[g].z, d3 = u[g].w;
                acc[0] = fmaf(w[g], __uint_as_float(d0 << 16),         acc[0]);
                acc[1] = fmaf(w[g], __uint_as_float(d0 & 0xffff0000u), acc[1]);
                acc[2] = fmaf(w[g], __uint_as_float(d1 << 16),         acc[2]);
                acc[3] = fmaf(w[g], __uint_as_float(d1 & 0xffff0000u), acc[3]);
                acc[4] = fmaf(w[g], __uint_as_float(d2 << 16),         acc[4]);
                acc[5] = fmaf(w[g], __uint_as_float(d2 & 0xffff0000u), acc[5]);
                acc[6] = fmaf(w[g], __uint_as_float(d3 << 16),         acc[6]);
                acc[7] = fmaf(w[g], __uint_as_float(d3 & 0xffff0000u), acc[7]);
            }
        }
    }

    // Reduce across the 8 edge-groups (lanes sharing fl).
    #pragma unroll
    for (int m = 8; m <= 32; m <<= 1) {
        #pragma unroll
        for (int j = 0; j < 8; ++j) acc[j] += __shfl_xor(acc[j], m);
    }

    if (eg == 0) {
        float* dst = out + (size_t)node * D + off;
        float4 o0 = make_float4(acc[0], acc[1], acc[2], acc[3]);
        float4 o1 = make_float4(acc[4], acc[5], acc[6], acc[7]);
        *(float4*)dst       = o0;
        *(float4*)(dst + 4) = o1;
    }
}

extern "C" void kernel_launch(void* const* d_in, const int* in_sizes, int n_in,
                              void* d_out, int out_size, void* d_ws, size_t ws_size,
                              hipStream_t stream) {
    const float* x    = (const float*)d_in[0];
    const float* W    = (const float*)d_in[1];
    const float* b    = (const float*)d_in[2];
    const float* ew   = (const float*)d_in[3];
    const int*   esrc = (const int*)d_in[4];
    const int*   edst = (const int*)d_in[5];
    float* out = (float*)d_out;

    const int N = in_sizes[0] / D;
    const int E = in_sizes[3];

    u16* sup = (u16*)d_ws;                                        // N*128 bf16
    int* rp  = (int*)((char*)d_ws + (size_t)N * D * sizeof(u16)); // N+1 ints
    u16* Wt  = (u16*)((char*)rp + ((size_t)N + 16) * sizeof(int));// 128*128 bf16

    hipLaunchKernelGGL(prep_kernel, dim3(64), dim3(256), 0, stream, W, Wt);
    hipLaunchKernelGGL(gemm_mfma_kernel, dim3((N + 63) / 64), dim3(256), 0, stream,
                       x, Wt, b, sup, N);
    hipLaunchKernelGGL(rowptr_kernel, dim3((E + 255) / 256), dim3(256), 0, stream,
                       edst, rp, E, N);

    int nblk_half = (N + 3) / 4;
    int grid_spmm = ((nblk_half + 3) / 4) * 8;
    hipLaunchKernelGGL(spmm_kernel, dim3(grid_spmm), dim3(256), 0, stream,
                       sup, ew, esrc, rp, out, N);
}